// Round 19
// baseline (326.635 us; speedup 1.0000x reference)
//
#include <hip/hip_runtime.h>

#define HID 128
#define WFRAG (HID*HID)
#define NXCD 8

typedef __attribute__((ext_vector_type(8))) short bf16x8;
typedef __attribute__((ext_vector_type(4))) float f32x4;

static __device__ __forceinline__ unsigned short f2bf(float f){
  unsigned u = __float_as_uint(f);
  unsigned r = (u + 0x7FFF + ((u >> 16) & 1)) >> 16;   // RNE
  return (unsigned short)r;
}
static __device__ __forceinline__ float bf2f_lo(unsigned u){ return __uint_as_float(u << 16); }
static __device__ __forceinline__ float bf2f_hi(unsigned u){ return __uint_as_float(u & 0xFFFF0000u); }

static __device__ __forceinline__ unsigned cvtpk(float lo, float hi){
  unsigned r;
  asm volatile("v_cvt_pk_bf16_f32 %0, %1, %2" : "=v"(r) : "v"(lo), "v"(hi));
  return r;
}

static __device__ __forceinline__ int xccid(){
  return __builtin_amdgcn_s_getreg((31<<11) | 20) & (NXCD-1);   // HW_REG_XCC_ID
}

// W fragment prep: own dispatch (R13: intra-dispatch producer->consumer
// races across non-coherent per-XCD L2s).
__global__ __launch_bounds__(256) void k_wprep(const float* __restrict__ Ws,
                                               unsigned short* __restrict__ Whi,
                                               unsigned short* __restrict__ Wlo){
  int layer = blockIdx.x;
  const float* W = Ws + (size_t)layer*HID*HID;
  for (int idx = threadIdx.x; idx < 2048; idx += 256){
    int lane = idx & 63, kstep = (idx>>6)&3, nblk = idx>>8;
    int col = 16*nblk + (lane&15);
    int k0  = 32*kstep + 8*(lane>>4);
    size_t obase = ((size_t)(layer*8 + nblk)*4 + kstep)*512 + (size_t)lane*8;
    for (int j = 0; j < 8; j++){
      float v = W[(size_t)(k0+j)*HID + col];
      unsigned short h = f2bf(v);
      float hf = __uint_as_float((unsigned)h << 16);
      Whi[obase+j] = h;
      Wlo[obase+j] = f2bf(v - hf);
    }
  }
}

// ---- gemm body, f32 input, plain bf16 H output. Streaming accesses are
// non-temporal via clang ext_vector (R18 fix: builtin rejects HIP float4):
// protects the fused pos-pass's fill8 counter lines from eviction. ----
static __device__ __forceinline__ void gemm_body_f32(int bid, const float* __restrict__ X,
                                                     const unsigned short* __restrict__ Whi,
                                                     const unsigned short* __restrict__ Wlo,
                                                     unsigned short* __restrict__ H2u, int N){
  int t = threadIdx.x, w = t>>6, l = t&63;
  int row0 = bid*32;
  int lrow = l & 15, lk = (l>>4)*8;
  f32x4 acc[2][2] = {};
#pragma unroll 1
  for (int kstep = 0; kstep < 4; kstep++){
    bf16x8 ahi[2], alo[2];
#pragma unroll
    for (int m = 0; m < 2; m++){
      int row = row0 + 16*m + lrow;
      if (row >= N) row = N-1;
      const f32x4* ap = (const f32x4*)(X + (size_t)row*HID + kstep*32 + lk);
      f32x4 a0 = __builtin_nontemporal_load(ap);
      f32x4 a1 = __builtin_nontemporal_load(ap+1);
      int4 hh, ll;
      hh.x = cvtpk(a0[0], a0[1]); hh.y = cvtpk(a0[2], a0[3]);
      hh.z = cvtpk(a1[0], a1[1]); hh.w = cvtpk(a1[2], a1[3]);
      ll.x = cvtpk(a0[0] - bf2f_lo(hh.x), a0[1] - bf2f_hi(hh.x));
      ll.y = cvtpk(a0[2] - bf2f_lo(hh.y), a0[3] - bf2f_hi(hh.y));
      ll.z = cvtpk(a1[0] - bf2f_lo(hh.z), a1[1] - bf2f_hi(hh.z));
      ll.w = cvtpk(a1[2] - bf2f_lo(hh.w), a1[3] - bf2f_hi(hh.w));
      ahi[m] = *(bf16x8*)&hh;
      alo[m] = *(bf16x8*)&ll;
    }
#pragma unroll
    for (int n = 0; n < 2; n++){
      size_t base = ((size_t)((2*w+n)*4 + kstep))*512 + (size_t)l*8;
      bf16x8 bhi = *(const bf16x8*)(Whi + base);
      bf16x8 blo = *(const bf16x8*)(Wlo + base);
#pragma unroll
      for (int m = 0; m < 2; m++){
        acc[m][n] = __builtin_amdgcn_mfma_f32_16x16x32_bf16(ahi[m], bhi, acc[m][n], 0, 0, 0);
        acc[m][n] = __builtin_amdgcn_mfma_f32_16x16x32_bf16(alo[m], bhi, acc[m][n], 0, 0, 0);
        acc[m][n] = __builtin_amdgcn_mfma_f32_16x16x32_bf16(ahi[m], blo, acc[m][n], 0, 0, 0);
      }
    }
  }
#pragma unroll
  for (int m = 0; m < 2; m++)
#pragma unroll
    for (int r = 0; r < 4; r++){
      int row = row0 + 16*m + 4*(l>>4) + r;
      if (row < N){
#pragma unroll
        for (int n = 0; n < 2; n++){
          int col = 16*(2*w+n) + lrow;
          __builtin_nontemporal_store(f2bf(acc[m][n][r]), &H2u[(size_t)row*HID + col]);
        }
      }
    }
}

// Fused: XCD-privatized position pass | gemm0 (MFMA backfill). R13-safe.
// pos stores non-temporal (streaming, consumed next dispatch).
__global__ __launch_bounds__(256) void k_pos8_gemm0(const int* __restrict__ dst, int* __restrict__ fill8,
                                                    int* __restrict__ pos, int E, int N, int Gp,
                                                    const float* __restrict__ X,
                                                    const unsigned short* __restrict__ Whi,
                                                    const unsigned short* __restrict__ Wlo,
                                                    unsigned short* __restrict__ H2u){
  int bid = blockIdx.x;
  if (bid < Gp){
    int e = bid*256 + threadIdx.x;
    if (e < E){
      int x = xccid();
      int d = __builtin_nontemporal_load(&dst[e]);
      int p = atomicAdd(&fill8[(size_t)x*N + d], 1);
      __builtin_nontemporal_store((x << 28) | p, &pos[e]);
    }
    return;
  }
  gemm_body_f32(bid - Gp, X, Whi, Wlo, H2u, N);
}

// Per-node: deg = sum of 8 per-XCD counts; block-scan -> rowstart; per-XCD
// bases xbase[x][n]; dinv.
__global__ __launch_bounds__(256) void k_alloc8(const int* __restrict__ fill8, int* __restrict__ deg,
                                                int* __restrict__ rowstart, int* __restrict__ xbase,
                                                float* __restrict__ dinv, int* __restrict__ cursor, int N){
  __shared__ int sm[256];
  __shared__ int sbase;
  int t = threadIdx.x;
  int n = blockIdx.x*256 + t;
  int c[NXCD];
  int d = 0;
  if (n < N){
#pragma unroll
    for (int x = 0; x < NXCD; x++){ c[x] = fill8[(size_t)x*N + n]; d += c[x]; }
  }
  sm[t] = d;
  __syncthreads();
  for (int off = 1; off < 256; off <<= 1){
    int v = (t >= off) ? sm[t-off] : 0;
    __syncthreads();
    sm[t] += v;
    __syncthreads();
  }
  if (t == 255) sbase = atomicAdd(cursor, sm[255]);
  __syncthreads();
  if (n < N){
    int rs = sbase + sm[t] - d;
    rowstart[n] = rs;
    deg[n] = d;
    dinv[n] = d > 0 ? rsqrtf((float)d) : 0.0f;
    int xb = rs;
#pragma unroll
    for (int x = 0; x < NXCD; x++){ xbase[(size_t)x*N + n] = xb; xb += c[x]; }
  }
}

// Atomic-free slot scatter (R15-proven form); slots = (src, dinv[src]).
__global__ __launch_bounds__(256) void k_scatter(const int* __restrict__ src, const int* __restrict__ dst,
                                                 const int* __restrict__ pos, const int* __restrict__ xbase,
                                                 const float* __restrict__ dinv,
                                                 int2* __restrict__ slots, int E, int N){
  int i0 = (blockIdx.x*256 + threadIdx.x)*2;
  if (i0 + 1 < E){
    int2 s = *(const int2*)(src + i0);
    int2 d = *(const int2*)(dst + i0);
    int2 p = *(const int2*)(pos + i0);
    int slot0 = xbase[(size_t)(p.x >> 28)*N + d.x] + (p.x & 0x0FFFFFFF);
    int slot1 = xbase[(size_t)(p.y >> 28)*N + d.y] + (p.y & 0x0FFFFFFF);
    slots[slot0] = make_int2(s.x, __float_as_int(dinv[s.x]));
    slots[slot1] = make_int2(s.y, __float_as_int(dinv[s.y]));
  } else if (i0 < E){
    int s = src[i0], d = dst[i0], p = pos[i0];
    slots[xbase[(size_t)(p >> 28)*N + d] + (p & 0x0FFFFFFF)] = make_int2(s, __float_as_int(dinv[s]));
  }
}

// gemm for bf16 input (layer >=1): exact bf16 A -> 2 MFMAs.
__global__ __launch_bounds__(256) void k_gemm_bf16(const unsigned short* __restrict__ Xb,
                                                   const unsigned short* __restrict__ Whi,
                                                   const unsigned short* __restrict__ Wlo,
                                                   unsigned short* __restrict__ H2u, int N){
  int t = threadIdx.x, w = t>>6, l = t&63;
  int row0 = blockIdx.x*32;
  int lrow = l & 15, lk = (l>>4)*8;
  f32x4 acc[2][2] = {};
#pragma unroll 1
  for (int kstep = 0; kstep < 4; kstep++){
    bf16x8 a[2];
#pragma unroll
    for (int m = 0; m < 2; m++){
      int row = row0 + 16*m + lrow;
      if (row >= N) row = N-1;
      a[m] = *(const bf16x8*)(Xb + (size_t)row*HID + kstep*32 + lk);
    }
#pragma unroll
    for (int n = 0; n < 2; n++){
      size_t base = ((size_t)((2*w+n)*4 + kstep))*512 + (size_t)l*8;
      bf16x8 bhi = *(const bf16x8*)(Whi + base);
      bf16x8 blo = *(const bf16x8*)(Wlo + base);
#pragma unroll
      for (int m = 0; m < 2; m++){
        acc[m][n] = __builtin_amdgcn_mfma_f32_16x16x32_bf16(a[m], bhi, acc[m][n], 0, 0, 0);
        acc[m][n] = __builtin_amdgcn_mfma_f32_16x16x32_bf16(a[m], blo, acc[m][n], 0, 0, 0);
      }
    }
  }
#pragma unroll
  for (int m = 0; m < 2; m++)
#pragma unroll
    for (int r = 0; r < 4; r++){
      int row = row0 + 16*m + 4*(l>>4) + r;
      if (row < N){
#pragma unroll
        for (int n = 0; n < 2; n++){
          int col = 16*(2*w+n) + lrow;
          H2u[(size_t)row*HID + col] = f2bf(acc[m][n][r]);
        }
      }
    }
}

// One wave per node; 16 lanes x uint4 per H row; 16 edges/iter predicated.
template<int OUTBF>
__global__ __launch_bounds__(256) void k_agg(const uint4* __restrict__ H4, const int2* __restrict__ slots,
                                             const int* __restrict__ rowstart, const int* __restrict__ deg,
                                             const float* __restrict__ dinv,
                                             const float* __restrict__ bias, void* __restrict__ outp, int N){
  int wid = threadIdx.x >> 6, lane = threadIdx.x & 63;
  int n = blockIdx.x*4 + wid;
  if (n >= N) return;
  int st = rowstart[n], cnt = deg[n];
  int g = lane >> 4, c = lane & 15;
  float a[8] = {0.f,0.f,0.f,0.f,0.f,0.f,0.f,0.f};
  for (int j = 0; j < cnt; j += 16){
    int cl = cnt - 1;
    int2 sl[4];
#pragma unroll
    for (int q = 0; q < 4; q++){
      int jj = j + 4*q + g;
      sl[q] = slots[st + (jj < cnt ? jj : cl)];
    }
    uint4 v[4];
#pragma unroll
    for (int q = 0; q < 4; q++) v[q] = H4[(size_t)sl[q].x*16 + c];
#pragma unroll
    for (int q = 0; q < 4; q++){
      float wq = (j + 4*q + g < cnt) ? __int_as_float(sl[q].y) : 0.f;
      a[0] += wq*bf2f_lo(v[q].x);
      a[1] += wq*bf2f_hi(v[q].x);
      a[2] += wq*bf2f_lo(v[q].y);
      a[3] += wq*bf2f_hi(v[q].y);
      a[4] += wq*bf2f_lo(v[q].z);
      a[5] += wq*bf2f_hi(v[q].z);
      a[6] += wq*bf2f_lo(v[q].w);
      a[7] += wq*bf2f_hi(v[q].w);
    }
  }
#pragma unroll
  for (int q = 0; q < 8; q++){
    a[q] += __shfl_xor(a[q], 16);
    a[q] += __shfl_xor(a[q], 32);
  }
  if (g == 0){
    float dv = dinv[n];
    const float4* b4 = (const float4*)bias;
    float4 b0 = b4[c*2], b1 = b4[c*2+1];
    float o[8];
    o[0]=dv*a[0]+b0.x; o[1]=dv*a[1]+b0.y; o[2]=dv*a[2]+b0.z; o[3]=dv*a[3]+b0.w;
    o[4]=dv*a[4]+b1.x; o[5]=dv*a[5]+b1.y; o[6]=dv*a[6]+b1.z; o[7]=dv*a[7]+b1.w;
    if (OUTBF){
      uint4 p;
      p.x = (unsigned)f2bf(o[0]) | ((unsigned)f2bf(o[1]) << 16);
      p.y = (unsigned)f2bf(o[2]) | ((unsigned)f2bf(o[3]) << 16);
      p.z = (unsigned)f2bf(o[4]) | ((unsigned)f2bf(o[5]) << 16);
      p.w = (unsigned)f2bf(o[6]) | ((unsigned)f2bf(o[7]) << 16);
      ((uint4*)outp)[(size_t)n*16 + c] = p;
    } else {
      float4* orow = (float4*)((float*)outp + (size_t)n*HID);
      orow[c*2]   = make_float4(o[0],o[1],o[2],o[3]);
      orow[c*2+1] = make_float4(o[4],o[5],o[6],o[7]);
    }
  }
}

extern "C" void kernel_launch(void* const* d_in, const int* in_sizes, int n_in,
                              void* d_out, int out_size, void* d_ws, size_t ws_size,
                              hipStream_t stream){
  const float* x  = (const float*)d_in[0];
  const int*   ei = (const int*)d_in[1];
  const float* Ws = (const float*)d_in[2];
  const float* bs = (const float*)d_in[3];
  const int N = in_sizes[0] / HID;
  const int E = in_sizes[1] / 2;
  const int L = in_sizes[2] / (HID*HID);   // == 2
  const int* src = ei;        // edge_index[0]
  const int* dst = ei + E;    // edge_index[1]
  const int NB = (N + 255)/256;

  char* w = (char*)d_ws;
  int*   fill8    = (int*)w;   w += (size_t)NXCD*N*4;
  int*   cursor   = (int*)w;   w += 64;
  size_t zbytes = (size_t)(w - (char*)d_ws);        // fill8 + cursor zeroed
  int*   deg      = (int*)w;   w += (size_t)N*4;
  float* dinv     = (float*)w; w += (size_t)N*4;
  int*   rowstart = (int*)w;   w += (size_t)N*4;
  int*   xbase    = (int*)w;   w += (size_t)NXCD*N*4;
  int*   pos      = (int*)w;   w += (size_t)E*4;
  int2*  slots    = (int2*)w;  w += (size_t)E*8 + 64;
  unsigned short* h2u = (unsigned short*)w; w += (size_t)N*HID*2;
  unsigned short* xb1 = (unsigned short*)w; w += (size_t)N*HID*2;
  unsigned short* whi = (unsigned short*)w; w += (size_t)L*WFRAG*2;
  unsigned short* wlo = (unsigned short*)w; w += (size_t)L*WFRAG*2;

  hipMemsetAsync(d_ws, 0, zbytes, stream);

  int Gp = (E + 255)/256;
  int Gs = (E/2 + 255)/256 + 1;
  int Gg = (N + 31)/32;
  int Ga = (N + 3)/4;

  k_wprep     <<<L, 256, 0, stream>>>(Ws, whi, wlo);
  k_pos8_gemm0<<<Gp + Gg, 256, 0, stream>>>(dst, fill8, pos, E, N, Gp, x, whi, wlo, h2u);
  k_alloc8    <<<NB, 256, 0, stream>>>(fill8, deg, rowstart, xbase, dinv, cursor, N);
  k_scatter   <<<Gs, 256, 0, stream>>>(src, dst, pos, xbase, dinv, slots, E, N);
  // layer 0: agg -> bf16 x1
  k_agg<1><<<Ga, 256, 0, stream>>>((const uint4*)h2u, slots, rowstart, deg,
                                   dinv, bs, (void*)xb1, N);
  // layer 1: bf16 gemm -> agg -> f32 out
  k_gemm_bf16<<<Gg, 256, 0, stream>>>(xb1, whi + WFRAG, wlo + WFRAG, h2u, N);
  k_agg<0><<<Ga, 256, 0, stream>>>((const uint4*)h2u, slots, rowstart, deg,
                                   dinv, bs + HID, d_out, N);
}

// Round 20
// 290.244 us; speedup vs baseline: 1.1254x; 1.1254x over previous
//
#include <hip/hip_runtime.h>

#define HID 128
#define WFRAG (HID*HID)
#define NXCD 8

typedef __attribute__((ext_vector_type(8))) short bf16x8;
typedef __attribute__((ext_vector_type(4))) float f32x4;

static __device__ __forceinline__ unsigned short f2bf(float f){
  unsigned u = __float_as_uint(f);
  unsigned r = (u + 0x7FFF + ((u >> 16) & 1)) >> 16;   // RNE
  return (unsigned short)r;
}
static __device__ __forceinline__ float bf2f_lo(unsigned u){ return __uint_as_float(u << 16); }
static __device__ __forceinline__ float bf2f_hi(unsigned u){ return __uint_as_float(u & 0xFFFF0000u); }

static __device__ __forceinline__ unsigned cvtpk(float lo, float hi){
  unsigned r;
  asm volatile("v_cvt_pk_bf16_f32 %0, %1, %2" : "=v"(r) : "v"(lo), "v"(hi));
  return r;
}

static __device__ __forceinline__ int xccid(){
  return __builtin_amdgcn_s_getreg((31<<11) | 20) & (NXCD-1);   // HW_REG_XCC_ID
}

// W fragment prep: own dispatch (R13: intra-dispatch producer->consumer
// races across non-coherent per-XCD L2s).
__global__ __launch_bounds__(256) void k_wprep(const float* __restrict__ Ws,
                                               unsigned short* __restrict__ Whi,
                                               unsigned short* __restrict__ Wlo){
  int layer = blockIdx.x;
  const float* W = Ws + (size_t)layer*HID*HID;
  for (int idx = threadIdx.x; idx < 2048; idx += 256){
    int lane = idx & 63, kstep = (idx>>6)&3, nblk = idx>>8;
    int col = 16*nblk + (lane&15);
    int k0  = 32*kstep + 8*(lane>>4);
    size_t obase = ((size_t)(layer*8 + nblk)*4 + kstep)*512 + (size_t)lane*8;
    for (int j = 0; j < 8; j++){
      float v = W[(size_t)(k0+j)*HID + col];
      unsigned short h = f2bf(v);
      float hf = __uint_as_float((unsigned)h << 16);
      Whi[obase+j] = h;
      Wlo[obase+j] = f2bf(v - hf);
    }
  }
}

// ---- gemm body, f32 input, plain bf16 H output (R17-proven form) ----
static __device__ __forceinline__ void gemm_body_f32(int bid, const float* __restrict__ X,
                                                     const unsigned short* __restrict__ Whi,
                                                     const unsigned short* __restrict__ Wlo,
                                                     unsigned short* __restrict__ H2u, int N){
  int t = threadIdx.x, w = t>>6, l = t&63;
  int row0 = bid*32;
  int lrow = l & 15, lk = (l>>4)*8;
  f32x4 acc[2][2] = {};
#pragma unroll 1
  for (int kstep = 0; kstep < 4; kstep++){
    bf16x8 ahi[2], alo[2];
#pragma unroll
    for (int m = 0; m < 2; m++){
      int row = row0 + 16*m + lrow;
      if (row >= N) row = N-1;
      const float* ap = X + (size_t)row*HID + kstep*32 + lk;
      float4 a0 = *(const float4*)ap;
      float4 a1 = *(const float4*)(ap+4);
      int4 hh, ll;
      hh.x = cvtpk(a0.x, a0.y); hh.y = cvtpk(a0.z, a0.w);
      hh.z = cvtpk(a1.x, a1.y); hh.w = cvtpk(a1.z, a1.w);
      ll.x = cvtpk(a0.x - bf2f_lo(hh.x), a0.y - bf2f_hi(hh.x));
      ll.y = cvtpk(a0.z - bf2f_lo(hh.y), a0.w - bf2f_hi(hh.y));
      ll.z = cvtpk(a1.x - bf2f_lo(hh.z), a1.y - bf2f_hi(hh.z));
      ll.w = cvtpk(a1.z - bf2f_lo(hh.w), a1.w - bf2f_hi(hh.w));
      ahi[m] = *(bf16x8*)&hh;
      alo[m] = *(bf16x8*)&ll;
    }
#pragma unroll
    for (int n = 0; n < 2; n++){
      size_t base = ((size_t)((2*w+n)*4 + kstep))*512 + (size_t)l*8;
      bf16x8 bhi = *(const bf16x8*)(Whi + base);
      bf16x8 blo = *(const bf16x8*)(Wlo + base);
#pragma unroll
      for (int m = 0; m < 2; m++){
        acc[m][n] = __builtin_amdgcn_mfma_f32_16x16x32_bf16(ahi[m], bhi, acc[m][n], 0, 0, 0);
        acc[m][n] = __builtin_amdgcn_mfma_f32_16x16x32_bf16(alo[m], bhi, acc[m][n], 0, 0, 0);
        acc[m][n] = __builtin_amdgcn_mfma_f32_16x16x32_bf16(ahi[m], blo, acc[m][n], 0, 0, 0);
      }
    }
  }
#pragma unroll
  for (int m = 0; m < 2; m++)
#pragma unroll
    for (int r = 0; r < 4; r++){
      int row = row0 + 16*m + 4*(l>>4) + r;
      if (row < N){
#pragma unroll
        for (int n = 0; n < 2; n++){
          int col = 16*(2*w+n) + lrow;
          H2u[(size_t)row*HID + col] = f2bf(acc[m][n][r]);
        }
      }
    }
}

// Fused: XCD-privatized position pass | gemm0 (MFMA backfill). R13-safe.
// R20: fill8 atomics at WORKGROUP scope — fill8[x][*] is only ever touched
// by XCD x (same L2), so the weaker scope lets the RMW run in the LOCAL L2
// instead of the MALL coherence point (R19 showed agent-scope atomics drag
// E*64B lines through the fabric regardless of L2 residency). Visibility to
// k_alloc8 comes from the kernel-boundary writeback.
__global__ __launch_bounds__(256) void k_pos8_gemm0(const int* __restrict__ dst, int* __restrict__ fill8,
                                                    int* __restrict__ pos, int E, int N, int Gp,
                                                    const float* __restrict__ X,
                                                    const unsigned short* __restrict__ Whi,
                                                    const unsigned short* __restrict__ Wlo,
                                                    unsigned short* __restrict__ H2u){
  int bid = blockIdx.x;
  if (bid < Gp){
    int e = bid*256 + threadIdx.x;
    if (e < E){
      int x = xccid();
      int d = dst[e];
      int p = __hip_atomic_fetch_add(&fill8[(size_t)x*N + d], 1,
                                     __ATOMIC_RELAXED, __HIP_MEMORY_SCOPE_WORKGROUP);
      pos[e] = (x << 28) | p;
    }
    return;
  }
  gemm_body_f32(bid - Gp, X, Whi, Wlo, H2u, N);
}

// Per-node: deg = sum of 8 per-XCD counts; block-scan -> rowstart; per-XCD
// bases xbase[x][n]; dinv.
__global__ __launch_bounds__(256) void k_alloc8(const int* __restrict__ fill8, int* __restrict__ deg,
                                                int* __restrict__ rowstart, int* __restrict__ xbase,
                                                float* __restrict__ dinv, int* __restrict__ cursor, int N){
  __shared__ int sm[256];
  __shared__ int sbase;
  int t = threadIdx.x;
  int n = blockIdx.x*256 + t;
  int c[NXCD];
  int d = 0;
  if (n < N){
#pragma unroll
    for (int x = 0; x < NXCD; x++){ c[x] = fill8[(size_t)x*N + n]; d += c[x]; }
  }
  sm[t] = d;
  __syncthreads();
  for (int off = 1; off < 256; off <<= 1){
    int v = (t >= off) ? sm[t-off] : 0;
    __syncthreads();
    sm[t] += v;
    __syncthreads();
  }
  if (t == 255) sbase = atomicAdd(cursor, sm[255]);
  __syncthreads();
  if (n < N){
    int rs = sbase + sm[t] - d;
    rowstart[n] = rs;
    deg[n] = d;
    dinv[n] = d > 0 ? rsqrtf((float)d) : 0.0f;
    int xb = rs;
#pragma unroll
    for (int x = 0; x < NXCD; x++){ xbase[(size_t)x*N + n] = xb; xb += c[x]; }
  }
}

// Atomic-free slot scatter (R15-proven form); slots = (src, dinv[src]).
__global__ __launch_bounds__(256) void k_scatter(const int* __restrict__ src, const int* __restrict__ dst,
                                                 const int* __restrict__ pos, const int* __restrict__ xbase,
                                                 const float* __restrict__ dinv,
                                                 int2* __restrict__ slots, int E, int N){
  int i0 = (blockIdx.x*256 + threadIdx.x)*2;
  if (i0 + 1 < E){
    int2 s = *(const int2*)(src + i0);
    int2 d = *(const int2*)(dst + i0);
    int2 p = *(const int2*)(pos + i0);
    int slot0 = xbase[(size_t)(p.x >> 28)*N + d.x] + (p.x & 0x0FFFFFFF);
    int slot1 = xbase[(size_t)(p.y >> 28)*N + d.y] + (p.y & 0x0FFFFFFF);
    slots[slot0] = make_int2(s.x, __float_as_int(dinv[s.x]));
    slots[slot1] = make_int2(s.y, __float_as_int(dinv[s.y]));
  } else if (i0 < E){
    int s = src[i0], d = dst[i0], p = pos[i0];
    slots[xbase[(size_t)(p >> 28)*N + d] + (p & 0x0FFFFFFF)] = make_int2(s, __float_as_int(dinv[s]));
  }
}

// gemm for bf16 input (layer >=1): exact bf16 A -> 2 MFMAs.
__global__ __launch_bounds__(256) void k_gemm_bf16(const unsigned short* __restrict__ Xb,
                                                   const unsigned short* __restrict__ Whi,
                                                   const unsigned short* __restrict__ Wlo,
                                                   unsigned short* __restrict__ H2u, int N){
  int t = threadIdx.x, w = t>>6, l = t&63;
  int row0 = blockIdx.x*32;
  int lrow = l & 15, lk = (l>>4)*8;
  f32x4 acc[2][2] = {};
#pragma unroll 1
  for (int kstep = 0; kstep < 4; kstep++){
    bf16x8 a[2];
#pragma unroll
    for (int m = 0; m < 2; m++){
      int row = row0 + 16*m + lrow;
      if (row >= N) row = N-1;
      a[m] = *(const bf16x8*)(Xb + (size_t)row*HID + kstep*32 + lk);
    }
#pragma unroll
    for (int n = 0; n < 2; n++){
      size_t base = ((size_t)((2*w+n)*4 + kstep))*512 + (size_t)l*8;
      bf16x8 bhi = *(const bf16x8*)(Whi + base);
      bf16x8 blo = *(const bf16x8*)(Wlo + base);
#pragma unroll
      for (int m = 0; m < 2; m++){
        acc[m][n] = __builtin_amdgcn_mfma_f32_16x16x32_bf16(a[m], bhi, acc[m][n], 0, 0, 0);
        acc[m][n] = __builtin_amdgcn_mfma_f32_16x16x32_bf16(a[m], blo, acc[m][n], 0, 0, 0);
      }
    }
  }
#pragma unroll
  for (int m = 0; m < 2; m++)
#pragma unroll
    for (int r = 0; r < 4; r++){
      int row = row0 + 16*m + 4*(l>>4) + r;
      if (row < N){
#pragma unroll
        for (int n = 0; n < 2; n++){
          int col = 16*(2*w+n) + lrow;
          H2u[(size_t)row*HID + col] = f2bf(acc[m][n][r]);
        }
      }
    }
}

// One wave per node; 16 lanes x uint4 per H row; 16 edges/iter predicated.
template<int OUTBF>
__global__ __launch_bounds__(256) void k_agg(const uint4* __restrict__ H4, const int2* __restrict__ slots,
                                             const int* __restrict__ rowstart, const int* __restrict__ deg,
                                             const float* __restrict__ dinv,
                                             const float* __restrict__ bias, void* __restrict__ outp, int N){
  int wid = threadIdx.x >> 6, lane = threadIdx.x & 63;
  int n = blockIdx.x*4 + wid;
  if (n >= N) return;
  int st = rowstart[n], cnt = deg[n];
  int g = lane >> 4, c = lane & 15;
  float a[8] = {0.f,0.f,0.f,0.f,0.f,0.f,0.f,0.f};
  for (int j = 0; j < cnt; j += 16){
    int cl = cnt - 1;
    int2 sl[4];
#pragma unroll
    for (int q = 0; q < 4; q++){
      int jj = j + 4*q + g;
      sl[q] = slots[st + (jj < cnt ? jj : cl)];
    }
    uint4 v[4];
#pragma unroll
    for (int q = 0; q < 4; q++) v[q] = H4[(size_t)sl[q].x*16 + c];
#pragma unroll
    for (int q = 0; q < 4; q++){
      float wq = (j + 4*q + g < cnt) ? __int_as_float(sl[q].y) : 0.f;
      a[0] += wq*bf2f_lo(v[q].x);
      a[1] += wq*bf2f_hi(v[q].x);
      a[2] += wq*bf2f_lo(v[q].y);
      a[3] += wq*bf2f_hi(v[q].y);
      a[4] += wq*bf2f_lo(v[q].z);
      a[5] += wq*bf2f_hi(v[q].z);
      a[6] += wq*bf2f_lo(v[q].w);
      a[7] += wq*bf2f_hi(v[q].w);
    }
  }
#pragma unroll
  for (int q = 0; q < 8; q++){
    a[q] += __shfl_xor(a[q], 16);
    a[q] += __shfl_xor(a[q], 32);
  }
  if (g == 0){
    float dv = dinv[n];
    const float4* b4 = (const float4*)bias;
    float4 b0 = b4[c*2], b1 = b4[c*2+1];
    float o[8];
    o[0]=dv*a[0]+b0.x; o[1]=dv*a[1]+b0.y; o[2]=dv*a[2]+b0.z; o[3]=dv*a[3]+b0.w;
    o[4]=dv*a[4]+b1.x; o[5]=dv*a[5]+b1.y; o[6]=dv*a[6]+b1.z; o[7]=dv*a[7]+b1.w;
    if (OUTBF){
      uint4 p;
      p.x = (unsigned)f2bf(o[0]) | ((unsigned)f2bf(o[1]) << 16);
      p.y = (unsigned)f2bf(o[2]) | ((unsigned)f2bf(o[3]) << 16);
      p.z = (unsigned)f2bf(o[4]) | ((unsigned)f2bf(o[5]) << 16);
      p.w = (unsigned)f2bf(o[6]) | ((unsigned)f2bf(o[7]) << 16);
      ((uint4*)outp)[(size_t)n*16 + c] = p;
    } else {
      float4* orow = (float4*)((float*)outp + (size_t)n*HID);
      orow[c*2]   = make_float4(o[0],o[1],o[2],o[3]);
      orow[c*2+1] = make_float4(o[4],o[5],o[6],o[7]);
    }
  }
}

extern "C" void kernel_launch(void* const* d_in, const int* in_sizes, int n_in,
                              void* d_out, int out_size, void* d_ws, size_t ws_size,
                              hipStream_t stream){
  const float* x  = (const float*)d_in[0];
  const int*   ei = (const int*)d_in[1];
  const float* Ws = (const float*)d_in[2];
  const float* bs = (const float*)d_in[3];
  const int N = in_sizes[0] / HID;
  const int E = in_sizes[1] / 2;
  const int L = in_sizes[2] / (HID*HID);   // == 2
  const int* src = ei;        // edge_index[0]
  const int* dst = ei + E;    // edge_index[1]
  const int NB = (N + 255)/256;

  char* w = (char*)d_ws;
  int*   fill8    = (int*)w;   w += (size_t)NXCD*N*4;
  int*   cursor   = (int*)w;   w += 64;
  size_t zbytes = (size_t)(w - (char*)d_ws);        // fill8 + cursor zeroed
  int*   deg      = (int*)w;   w += (size_t)N*4;
  float* dinv     = (float*)w; w += (size_t)N*4;
  int*   rowstart = (int*)w;   w += (size_t)N*4;
  int*   xbase    = (int*)w;   w += (size_t)NXCD*N*4;
  int*   pos      = (int*)w;   w += (size_t)E*4;
  int2*  slots    = (int2*)w;  w += (size_t)E*8 + 64;
  unsigned short* h2u = (unsigned short*)w; w += (size_t)N*HID*2;
  unsigned short* xb1 = (unsigned short*)w; w += (size_t)N*HID*2;
  unsigned short* whi = (unsigned short*)w; w += (size_t)L*WFRAG*2;
  unsigned short* wlo = (unsigned short*)w; w += (size_t)L*WFRAG*2;

  hipMemsetAsync(d_ws, 0, zbytes, stream);

  int Gp = (E + 255)/256;
  int Gs = (E/2 + 255)/256 + 1;
  int Gg = (N + 31)/32;
  int Ga = (N + 3)/4;

  k_wprep     <<<L, 256, 0, stream>>>(Ws, whi, wlo);
  k_pos8_gemm0<<<Gp + Gg, 256, 0, stream>>>(dst, fill8, pos, E, N, Gp, x, whi, wlo, h2u);
  k_alloc8    <<<NB, 256, 0, stream>>>(fill8, deg, rowstart, xbase, dinv, cursor, N);
  k_scatter   <<<Gs, 256, 0, stream>>>(src, dst, pos, xbase, dinv, slots, E, N);
  // layer 0: agg -> bf16 x1
  k_agg<1><<<Ga, 256, 0, stream>>>((const uint4*)h2u, slots, rowstart, deg,
                                   dinv, bs, (void*)xb1, N);
  // layer 1: bf16 gemm -> agg -> f32 out
  k_gemm_bf16<<<Gg, 256, 0, stream>>>(xb1, whi + WFRAG, wlo + WFRAG, h2u, N);
  k_agg<0><<<Ga, 256, 0, stream>>>((const uint4*)h2u, slots, rowstart, deg,
                                   dinv, bs + HID, d_out, N);
}